// Round 8
// baseline (609.253 us; speedup 1.0000x reference)
//
#include <hip/hip_runtime.h>
#include <stdint.h>

#define HID   128
#define OUT   4096
#define NWG   16          // persistent EP workgroups, slice = 256 cols each
#define SLICE 256         // OUT / NWG
#define NT    512
#define NXB   128         // one-shot xW1 worker blocks
#define RPX   512         // rows per xW1 block (65536 / 128)
#define NSLOT 4           // partial-buffer ring depth (deferred check needs >2)

typedef unsigned long long u64;
typedef unsigned int v2u __attribute__((ext_vector_type(2)));

__device__ __forceinline__ u64 pk(uint32_t tag, float v) {
  return ((u64)tag << 32) | (u64)__float_as_uint(v);
}

// ---- VALU cross-lane primitives (guide-verified builtins only) -----------------
// permlane32_swap: exchanges vdst.hi32lanes <-> src.lo32lanes; returns both results.
// We sum the two outputs, so the {vdst,src} result-order convention cannot matter:
// sum = a[l]+a[l+32] (lanes<32, row r) / b[l-32]+b[l] (lanes>=32, row r+8).
__device__ __forceinline__ float plane32_fold(float a, float b) {
  const v2u r = __builtin_amdgcn_permlane32_swap(__float_as_uint(a), __float_as_uint(b),
                                                 false, false);
  return __uint_as_float(r.x) + __uint_as_float(r.y);
}
// DPP row_ror:8 (ctrl 0x128): within each 16-lane row, rotate by 8 == lane^8.
__device__ __forceinline__ float dpp_ror8(float x) {
  return __int_as_float(
      __builtin_amdgcn_update_dpp(0, __float_as_int(x), 0x128, 0xF, 0xF, true));
}
// quad_perm {2,3,0,1}=0x4E => xor2 ; {1,0,3,2}=0xB1 => xor1 (final fold stages).
__device__ __forceinline__ float dpp_add_xor2(float x) {
  const int y = __builtin_amdgcn_update_dpp(0, __float_as_int(x), 0x4E, 0xF, 0xF, true);
  return x + __int_as_float(y);
}
__device__ __forceinline__ float dpp_add_xor1(float x) {
  const int y = __builtin_amdgcn_update_dpp(0, __float_as_int(x), 0xB1, 0xF, 0xF, true);
  return x + __int_as_float(y);
}

// lgkm-only barrier: syncs LDS producers/consumers WITHOUT draining vmcnt, so the
// agent-scope publish store and the prefetched poll loads stay in flight across it.
// sched_barrier(0) fences stop the compiler from moving memory ops over it (rule #18).
__device__ __forceinline__ void bar_lgkm() {
  __builtin_amdgcn_sched_barrier(0);
  asm volatile("s_waitcnt lgkmcnt(0)" ::: "memory");
  __builtin_amdgcn_s_barrier();
  __builtin_amdgcn_sched_barrier(0);
}

// blockIdx < NWG: persistent EP workgroup. blockIdx >= NWG: one-shot xW1 worker.
__global__ __launch_bounds__(NT, 1) void k_all(
    const float* __restrict__ x,
    const float* __restrict__ W1,
    const float* __restrict__ W2,
    const float* __restrict__ b_h,
    const float* __restrict__ b_out,
    const float* __restrict__ h0,
    const float* __restrict__ o0,
    const int* __restrict__ n_iter_p,
    const float* __restrict__ eps_p,
    u64* __restrict__ pbuf,   // [NSLOT][NWG][HID] tagged h-gradient partials
    u64* __restrict__ xw1p,   // [NXB][HID] tagged xW1 partials
    float* __restrict__ out) {

  __shared__ __attribute__((aligned(16))) float red[8 * SLICE];  // 8 KB (also xW1 scratch)
  __shared__ __attribute__((aligned(16))) float rh_s[HID];
  __shared__ __attribute__((aligned(16))) float ro_s[SLICE];

  const int t = threadIdx.x;

  if (blockIdx.x >= NWG) {
    // ---------------- xW1 worker: partial of clip(x,0,1) @ W1 over 512 rows ------
    const int b = blockIdx.x - NWG;
    const int c4 = (t & 31) * 4;
    const int rseg = t >> 5;            // 0..15
    const int r0 = b * RPX + rseg * 32;
    float4 acc = make_float4(0.f, 0.f, 0.f, 0.f);
#pragma unroll 8
    for (int k = 0; k < 32; ++k) {
      const int r = r0 + k;
      const float rx = fminf(fmaxf(x[r], 0.f), 1.f);
      const float4 wv = *(const float4*)&W1[(size_t)r * HID + c4];
      acc.x = fmaf(rx, wv.x, acc.x); acc.y = fmaf(rx, wv.y, acc.y);
      acc.z = fmaf(rx, wv.z, acc.z); acc.w = fmaf(rx, wv.w, acc.w);
    }
    *(float4*)&red[rseg * HID + c4] = acc;   // 16*128 = 2048 floats, fits red exactly
    __syncthreads();
    if (t < HID) {
      float s = 0.f;
#pragma unroll
      for (int k = 0; k < 16; k += 4)
        s += (red[k*HID + t] + red[(k+1)*HID + t]) + (red[(k+2)*HID + t] + red[(k+3)*HID + t]);
      __hip_atomic_store(&xw1p[b * HID + t], pk(1u, s),
                         __ATOMIC_RELAXED, __HIP_MEMORY_SCOPE_AGENT);
    }
    return;
  }

  // ---------------- persistent EP workgroup ---------------------------------------
  const int wg = blockIdx.x;
  const int cg = t & 63;               // lane id; owns cols cg + 64*k (k=0..3)
  const int rg = t >> 6;               // wave id; owns rows rg*16 .. rg*16+15
  const int n_iter = *n_iter_p;
  const float eps  = *eps_p;

  // ---- W2 chunk into registers: w2[r][k] = W2[rg*16+r][wg*256 + cg + 64k] ----
  float w2[16][4];
  {
    const float* wp = W2 + (size_t)(rg * 16) * OUT + wg * SLICE + cg;
#pragma unroll
    for (int r = 0; r < 16; ++r)
#pragma unroll
      for (int k = 0; k < 4; ++k)
        w2[r][k] = wp[(size_t)r * OUT + 64 * k];
  }
#pragma unroll
  for (int r = 0; r < 16; ++r)
    asm volatile("" : "+v"(w2[r][0]), "+v"(w2[r][1]), "+v"(w2[r][2]), "+v"(w2[r][3]));

  // ---- gather xW1 partials: BATCHED unconditional tagged loads, fixed-order sum ----
  float bhx = 0.f, hh = 0.f, mh = 0.f, vh = 0.f;
  if (t < HID) {
    float s = 0.f;
#pragma unroll 1
    for (int ch = 0; ch < 8; ++ch) {
      u64 v[16];
      for (;;) {
#pragma unroll
        for (int k = 0; k < 16; ++k)
          v[k] = __hip_atomic_load(&xw1p[(ch * 16 + k) * HID + t],
                                   __ATOMIC_RELAXED, __HIP_MEMORY_SCOPE_AGENT);
        uint32_t bad = 0u;
#pragma unroll
        for (int k = 0; k < 16; ++k) bad |= ((uint32_t)(v[k] >> 32)) ^ 1u;
        if (bad == 0u) break;
        __builtin_amdgcn_s_sleep(2);
      }
#pragma unroll
      for (int k = 0; k < 16; ++k) s += __uint_as_float((uint32_t)v[k]);
    }
    bhx = b_h[t] + s;
    hh  = h0[t];
    rh_s[t] = fminf(fmaxf(hh, 0.f), 1.f);
  }
  // o-state: one column per thread for t < SLICE only (SLICE=256 < NT)
  float oo = 0.f, mo = 0.f, vo = 0.f, bo = 0.f;
  if (t < SLICE) {
    oo = o0[wg * SLICE + t];
    bo = b_out[wg * SLICE + t];
    ro_s[t] = fminf(fmaxf(oo, 0.f), 1.f);
  }
  __syncthreads();

  // bp1/bp2 hold 0.9^it / 0.999^it at the deferred-check point (h uses step t1=it);
  // they advance before the o-update (o uses t1=it+1).
  float bp1 = 1.f, bp2 = 1.f;

  for (int it = 0; it < n_iter; ++it) {
    // ---- prefetch the partials this iteration's check consumes (tag = it, slot
    //      (it-1)&3, published by peers mid-iteration it-1, i.e. a full period ago
    //      -> store-visibility at MALL is long complete: systematically FRESH).
    //      Issued as the FIRST ops after B3; the only wait is the check's vmcnt,
    //      ~PassB+fold (~700 cyc) later, hiding most of the load RT. ----
    u64 pref[16];
    if (t < HID && it > 0) {
      const u64* pn = pbuf + (size_t)((it - 1) & (NSLOT - 1)) * (NWG * HID) + t;
#pragma unroll
      for (int wi = 0; wi < 16; ++wi)
        pref[wi] = __hip_atomic_load(pn + wi * HID,
                                     __ATOMIC_RELAXED, __HIP_MEMORY_SCOPE_AGENT);
    }

    // ---- Pass B (registers): rows rg*16..+15, partial over this thread's 4 cols ----
    float aB[16];
    {
      float rov[4];
#pragma unroll
      for (int k = 0; k < 4; ++k) rov[k] = ro_s[cg + 64 * k];   // stride-1/lane, conflict-free
#pragma unroll
      for (int r = 0; r < 16; ++r) {
        float a = w2[r][0] * rov[0];
#pragma unroll
        for (int k = 1; k < 4; ++k) a = fmaf(w2[r][k], rov[k], a);
        aB[r] = a;
      }
    }
    // ---- in-wave fold (same tree as R6): xor32 on permlane32_swap (VALU),
    //      xor16 shfl (DS), xor8 DPP row_ror (VALU), xor4 shfl (DS),
    //      xor2/xor1 quad_perm (VALU). Publish map: lanes cg%4==0 hold row cg>>2. ----
    {
#pragma unroll
      for (int r = 0; r < 8; ++r)     // xor32: 16 -> 8 rows (VALU permlane swap)
        aB[r] = plane32_fold(aB[r], aB[r + 8]);
#pragma unroll
      for (int r = 0; r < 4; ++r) {   // xor16: 8 -> 4 (DS shfl, kept)
        const float keep = (cg & 16) ? aB[r + 4] : aB[r];
        const float send = (cg & 16) ? aB[r]     : aB[r + 4];
        aB[r] = keep + __shfl_xor(send, 16, 64);
      }
#pragma unroll
      for (int r = 0; r < 2; ++r) {   // xor8: 4 -> 2 (VALU, row_ror:8 == lane^8)
        const float keep = (cg & 8) ? aB[r + 2] : aB[r];
        const float send = (cg & 8) ? aB[r]     : aB[r + 2];
        aB[r] = keep + dpp_ror8(send);
      }
      {                               // xor4: 2 -> 1 (DS shfl, kept)
        const float keep = (cg & 4) ? aB[1] : aB[0];
        const float send = (cg & 4) ? aB[0] : aB[1];
        aB[0] = keep + __shfl_xor(send, 4, 64);
      }
      aB[0] = dpp_add_xor2(aB[0]);    // lane bits 1,0 (VALU)
      aB[0] = dpp_add_xor1(aB[0]);
    }

    // ---- deferred check: consume PassB(it-1) partials (prefetched at loop top).
    //      Fresh in steady state -> only residual load RT (~300-500 cyc) exposed. ----
    if (t < HID && it > 0) {
      const uint32_t tagc = (uint32_t)it;     // published at iteration it-1
      u64 v[16];
#pragma unroll
      for (int wi = 0; wi < 16; ++wi) v[wi] = pref[wi];
      uint32_t bad = 0u;
#pragma unroll
      for (int wi = 0; wi < 16; ++wi) bad |= ((uint32_t)(v[wi] >> 32)) ^ tagc;
      if (bad != 0u) {                        // prefetch was stale: retry loop
        u64* pc = pbuf + (size_t)((it - 1) & (NSLOT - 1)) * (NWG * HID);
        do {
#pragma unroll
          for (int wi = 0; wi < 16; ++wi)
            v[wi] = __hip_atomic_load(&pc[wi * HID + t],
                                      __ATOMIC_RELAXED, __HIP_MEMORY_SCOPE_AGENT);
          bad = 0u;
#pragma unroll
          for (int wi = 0; wi < 16; ++wi) bad |= ((uint32_t)(v[wi] >> 32)) ^ tagc;
          if (bad != 0u) __builtin_amdgcn_s_sleep(1);
        } while (bad != 0u);
      }
      float gv[16];
#pragma unroll
      for (int wi = 0; wi < 16; ++wi) gv[wi] = __uint_as_float((uint32_t)v[wi]);
      const float gsum = (((gv[0] + gv[1]) + (gv[2] + gv[3]))
                        + ((gv[4] + gv[5]) + (gv[6] + gv[7])))
                       + (((gv[8] + gv[9]) + (gv[10] + gv[11]))
                        + ((gv[12] + gv[13]) + (gv[14] + gv[15])));
      const float c1h = 1.f / (1.f - bp1);    // bp1 = 0.9^it here (pre-advance)
      const float c2h = 1.f / (1.f - bp2);
      const float rh_old = fminf(fmaxf(hh, 0.f), 1.f);
      const float g = (hh >= 0.f && hh <= 1.f) ? (rh_old - bhx - gsum) : 0.f;
      mh = 0.9f * mh + 0.1f * g;
      vh = 0.999f * vh + 0.001f * g * g;
      hh -= eps * (mh * c1h) / (sqrtf(vh * c2h) + 1e-8f);
      rh_s[t] = fminf(fmaxf(hh, 0.f), 1.f);   // rh(it), consumed by Pass A below
    }

    // ---- publish tagged partial (row = rg*16 + cg/4, lanes cg%4==0).
    //      After the check, so the check's implicit vmcnt covers only the prefetch. ----
    if ((cg & 3) == 0) {
      u64* pp = pbuf + (size_t)(it & (NSLOT - 1)) * (NWG * HID)
                     + wg * HID + rg * 16 + (cg >> 2);
      __hip_atomic_store(pp, pk((uint32_t)(it + 1), aB[0]),
                         __ATOMIC_RELAXED, __HIP_MEMORY_SCOPE_AGENT);
    }

    bp1 *= 0.9f; bp2 *= 0.999f;               // now 0.9^(it+1): o-update factors
    const float c1 = 1.f / (1.f - bp1);
    const float c2 = 1.f / (1.f - bp2);

    bar_lgkm();   // B1: rh_s(it) visible to all waves

    // ---- Pass A: r_h @ W2 over this thread's rows ----
    {
      float aA[4] = {0.f, 0.f, 0.f, 0.f};
#pragma unroll
      for (int r = 0; r < 16; ++r) {
        const float rh = rh_s[rg * 16 + r];          // wave-uniform broadcast
#pragma unroll
        for (int k = 0; k < 4; ++k) aA[k] = fmaf(w2[r][k], rh, aA[k]);
      }
#pragma unroll
      for (int k = 0; k < 4; ++k)
        red[rg * SLICE + cg + 64 * k] = aA[k];       // stride-1/lane, conflict-free
    }
    bar_lgkm();   // B2: red visible

    // ---- g_o + Adam(o): one column (= t) per thread, t < SLICE ----
    if (t < SLICE) {
      const float s = ((red[t] + red[SLICE + t]) + (red[2*SLICE + t] + red[3*SLICE + t]))
                    + ((red[4*SLICE + t] + red[5*SLICE + t]) + (red[6*SLICE + t] + red[7*SLICE + t]));
      const float ro_old = fminf(fmaxf(oo, 0.f), 1.f);
      const float g = (oo >= 0.f && oo <= 1.f) ? (ro_old - bo - s) : 0.f;
      mo = 0.9f * mo + 0.1f * g;
      vo = 0.999f * vo + 0.001f * g * g;
      oo -= eps * (mo * c1) / (sqrtf(vo * c2) + 1e-8f);
      ro_s[t] = fminf(fmaxf(oo, 0.f), 1.f);          // ro(it+1), read next iter
    }

    bar_lgkm();   // B3: ro_s(it+1) visible for next Pass B
  }

  if (t < SLICE) out[wg * SLICE + t] = oo;
}

// ---------------- launcher ----------------------------------------------------------
extern "C" void kernel_launch(void* const* d_in, const int* in_sizes, int n_in,
                              void* d_out, int out_size, void* d_ws, size_t ws_size,
                              hipStream_t stream) {
  const float* x     = (const float*)d_in[0];
  const float* W1    = (const float*)d_in[1];
  const float* W2    = (const float*)d_in[2];
  // d_in[3] = b_in (unused by the reference)
  const float* b_h   = (const float*)d_in[4];
  const float* b_out = (const float*)d_in[5];
  const float* h0    = (const float*)d_in[6];
  const float* o0    = (const float*)d_in[7];
  const int*   nit   = (const int*)d_in[8];
  const float* eps   = (const float*)d_in[9];

  u64*   pbuf = (u64*)d_ws;                         // [4][16][128] u64 = 64 KB
  u64*   xw1p = (u64*)((char*)d_ws + 65536);        // [128][128] u64 = 128 KB
  float* out  = (float*)d_out;

  // no memset needed: poisoned 0xAAAAAAAA tags never match (xw1 tag=1, iter tags=1..n)
  k_all<<<dim3(NWG + NXB), dim3(NT), 0, stream>>>(x, W1, W2, b_h, b_out, h0, o0,
                                                  nit, eps, pbuf, xw1p, out);
}

// Round 9
// 498.926 us; speedup vs baseline: 1.2211x; 1.2211x over previous
//
#include <hip/hip_runtime.h>
#include <stdint.h>

#define HID   128
#define OUT   4096
#define NWG   16          // persistent EP workgroups, slice = 256 cols each
#define SLICE 256         // OUT / NWG
#define NT    512
#define NXB   128         // one-shot xW1 worker blocks
#define RPX   512         // rows per xW1 block (65536 / 128)
#define NSLOT 4           // partial-buffer ring depth (deferred check needs >2)
// LDS pad: total static LDS ~98 KB > 160/2 KB ensures the CP can never co-schedule
// two blocks on one CU -> each EP workgroup owns its CU's VALU/LDS exclusively.
#define REDPAD 22528

typedef unsigned long long u64;
typedef unsigned int v2u __attribute__((ext_vector_type(2)));

__device__ __forceinline__ u64 pk(uint32_t tag, float v) {
  return ((u64)tag << 32) | (u64)__float_as_uint(v);
}

// ---- VALU cross-lane primitives (guide-verified builtins only) -----------------
// permlane32_swap: exchanges vdst.hi32lanes <-> src.lo32lanes; returns both results.
// We sum the two outputs, so the {vdst,src} result-order convention cannot matter:
// sum = a[l]+a[l+32] (lanes<32, row r) / b[l-32]+b[l] (lanes>=32, row r+8).
__device__ __forceinline__ float plane32_fold(float a, float b) {
  const v2u r = __builtin_amdgcn_permlane32_swap(__float_as_uint(a), __float_as_uint(b),
                                                 false, false);
  return __uint_as_float(r.x) + __uint_as_float(r.y);
}
// DPP row_ror:8 (ctrl 0x128): within each 16-lane row, rotate by 8 == lane^8.
__device__ __forceinline__ float dpp_ror8(float x) {
  return __int_as_float(
      __builtin_amdgcn_update_dpp(0, __float_as_int(x), 0x128, 0xF, 0xF, true));
}
// quad_perm {2,3,0,1}=0x4E => xor2 ; {1,0,3,2}=0xB1 => xor1 (final fold stages).
__device__ __forceinline__ float dpp_add_xor2(float x) {
  const int y = __builtin_amdgcn_update_dpp(0, __float_as_int(x), 0x4E, 0xF, 0xF, true);
  return x + __int_as_float(y);
}
__device__ __forceinline__ float dpp_add_xor1(float x) {
  const int y = __builtin_amdgcn_update_dpp(0, __float_as_int(x), 0xB1, 0xF, 0xF, true);
  return x + __int_as_float(y);
}

// lgkm-only barrier: syncs LDS producers/consumers WITHOUT draining vmcnt, so the
// agent-scope publish store and the prefetched poll loads stay in flight across it.
// sched_barrier(0) fences stop the compiler from moving memory ops over it (rule #18).
__device__ __forceinline__ void bar_lgkm() {
  __builtin_amdgcn_sched_barrier(0);
  asm volatile("s_waitcnt lgkmcnt(0)" ::: "memory");
  __builtin_amdgcn_s_barrier();
  __builtin_amdgcn_sched_barrier(0);
}

// blockIdx < NWG: persistent EP workgroup. blockIdx >= NWG: one-shot xW1 worker.
__global__ __launch_bounds__(NT, 1) void k_all(
    const float* __restrict__ x,
    const float* __restrict__ W1,
    const float* __restrict__ W2,
    const float* __restrict__ b_h,
    const float* __restrict__ b_out,
    const float* __restrict__ h0,
    const float* __restrict__ o0,
    const int* __restrict__ n_iter_p,
    const float* __restrict__ eps_p,
    u64* __restrict__ pbuf,   // [NSLOT][NWG][HID] tagged h-gradient partials
    u64* __restrict__ xw1p,   // [NXB][HID] tagged xW1 partials
    float* __restrict__ out) {

  // red's tail (REDPAD floats) is never indexed: it exists only to inflate the
  // static LDS footprint past 80 KB (anti-packing guarantee, see #define above).
  __shared__ __attribute__((aligned(16))) float red[8 * SLICE + REDPAD];
  __shared__ __attribute__((aligned(16))) float rh_s[HID];
  __shared__ __attribute__((aligned(16))) float ro_s[SLICE];

  const int t = threadIdx.x;

  if (blockIdx.x >= NWG) {
    // ---------------- xW1 worker: partial of clip(x,0,1) @ W1 over 512 rows ------
    const int b = blockIdx.x - NWG;
    const int c4 = (t & 31) * 4;
    const int rseg = t >> 5;            // 0..15
    const int r0 = b * RPX + rseg * 32;
    float4 acc = make_float4(0.f, 0.f, 0.f, 0.f);
#pragma unroll 8
    for (int k = 0; k < 32; ++k) {
      const int r = r0 + k;
      const float rx = fminf(fmaxf(x[r], 0.f), 1.f);
      const float4 wv = *(const float4*)&W1[(size_t)r * HID + c4];
      acc.x = fmaf(rx, wv.x, acc.x); acc.y = fmaf(rx, wv.y, acc.y);
      acc.z = fmaf(rx, wv.z, acc.z); acc.w = fmaf(rx, wv.w, acc.w);
    }
    *(float4*)&red[rseg * HID + c4] = acc;   // 16*128 = 2048 floats
    __syncthreads();
    if (t < HID) {
      float s = 0.f;
#pragma unroll
      for (int k = 0; k < 16; k += 4)
        s += (red[k*HID + t] + red[(k+1)*HID + t]) + (red[(k+2)*HID + t] + red[(k+3)*HID + t]);
      __hip_atomic_store(&xw1p[b * HID + t], pk(1u, s),
                         __ATOMIC_RELAXED, __HIP_MEMORY_SCOPE_AGENT);
    }
    return;
  }

  // ---------------- persistent EP workgroup ---------------------------------------
  const int wg = blockIdx.x;
  const int cg = t & 63;               // lane id; owns cols cg + 64*k (k=0..3)
  const int rg = t >> 6;               // wave id; owns rows rg*16 .. rg*16+15
  const int n_iter = *n_iter_p;
  const float eps  = *eps_p;

  // ---- W2 chunk into registers: w2[r][k] = W2[rg*16+r][wg*256 + cg + 64k] ----
  float w2[16][4];
  {
    const float* wp = W2 + (size_t)(rg * 16) * OUT + wg * SLICE + cg;
#pragma unroll
    for (int r = 0; r < 16; ++r)
#pragma unroll
      for (int k = 0; k < 4; ++k)
        w2[r][k] = wp[(size_t)r * OUT + 64 * k];
  }
#pragma unroll
  for (int r = 0; r < 16; ++r)
    asm volatile("" : "+v"(w2[r][0]), "+v"(w2[r][1]), "+v"(w2[r][2]), "+v"(w2[r][3]));

  // ---- gather xW1 partials: BATCHED unconditional tagged loads, fixed-order sum ----
  float bhx = 0.f, hh = 0.f, mh = 0.f, vh = 0.f;
  if (t < HID) {
    float s = 0.f;
#pragma unroll 1
    for (int ch = 0; ch < 8; ++ch) {
      u64 v[16];
      for (;;) {
#pragma unroll
        for (int k = 0; k < 16; ++k)
          v[k] = __hip_atomic_load(&xw1p[(ch * 16 + k) * HID + t],
                                   __ATOMIC_RELAXED, __HIP_MEMORY_SCOPE_AGENT);
        uint32_t bad = 0u;
#pragma unroll
        for (int k = 0; k < 16; ++k) bad |= ((uint32_t)(v[k] >> 32)) ^ 1u;
        if (bad == 0u) break;
        __builtin_amdgcn_s_sleep(2);
      }
#pragma unroll
      for (int k = 0; k < 16; ++k) s += __uint_as_float((uint32_t)v[k]);
    }
    bhx = b_h[t] + s;
    hh  = h0[t];
    rh_s[t] = fminf(fmaxf(hh, 0.f), 1.f);
  }
  // o-state: one column per thread for t < SLICE only (SLICE=256 < NT)
  float oo = 0.f, mo = 0.f, vo = 0.f, bo = 0.f;
  if (t < SLICE) {
    oo = o0[wg * SLICE + t];
    bo = b_out[wg * SLICE + t];
    ro_s[t] = fminf(fmaxf(oo, 0.f), 1.f);
  }
  __syncthreads();

  // bp1/bp2 hold 0.9^it / 0.999^it at the deferred-check point (h uses step t1=it);
  // they advance before the o-update (o uses t1=it+1).
  float bp1 = 1.f, bp2 = 1.f;
  u64 pref[16];
#pragma unroll
  for (int wi = 0; wi < 16; ++wi) pref[wi] = 0;   // prefetched partials for next check

  for (int it = 0; it < n_iter; ++it) {
    // ---- Pass B (registers): rows rg*16..+15, partial over this thread's 4 cols ----
    float aB[16];
    {
      float rov[4];
#pragma unroll
      for (int k = 0; k < 4; ++k) rov[k] = ro_s[cg + 64 * k];   // stride-1/lane, conflict-free
#pragma unroll
      for (int r = 0; r < 16; ++r) {
        float a = w2[r][0] * rov[0];
#pragma unroll
        for (int k = 1; k < 4; ++k) a = fmaf(w2[r][k], rov[k], a);
        aB[r] = a;
      }
    }
    // ---- in-wave fold (same tree as R6): xor32 on permlane32_swap (VALU),
    //      xor16 shfl (DS), xor8 DPP row_ror (VALU), xor4 shfl (DS),
    //      xor2/xor1 quad_perm (VALU). Publish map: lanes cg%4==0 hold row cg>>2. ----
    {
#pragma unroll
      for (int r = 0; r < 8; ++r)     // xor32: 16 -> 8 rows (VALU permlane swap)
        aB[r] = plane32_fold(aB[r], aB[r + 8]);
#pragma unroll
      for (int r = 0; r < 4; ++r) {   // xor16: 8 -> 4 (DS shfl, kept)
        const float keep = (cg & 16) ? aB[r + 4] : aB[r];
        const float send = (cg & 16) ? aB[r]     : aB[r + 4];
        aB[r] = keep + __shfl_xor(send, 16, 64);
      }
#pragma unroll
      for (int r = 0; r < 2; ++r) {   // xor8: 4 -> 2 (VALU, row_ror:8 == lane^8)
        const float keep = (cg & 8) ? aB[r + 2] : aB[r];
        const float send = (cg & 8) ? aB[r]     : aB[r + 2];
        aB[r] = keep + dpp_ror8(send);
      }
      {                               // xor4: 2 -> 1 (DS shfl, kept)
        const float keep = (cg & 4) ? aB[1] : aB[0];
        const float send = (cg & 4) ? aB[0] : aB[1];
        aB[0] = keep + __shfl_xor(send, 4, 64);
      }
      aB[0] = dpp_add_xor2(aB[0]);    // lane bits 1,0 (VALU)
      aB[0] = dpp_add_xor1(aB[0]);
    }

    // ---- deferred check: consume PassB(it-1) partials (prefetched last iteration;
    //      ~1600+ cyc of issue-to-wait distance -> MALL RT fully hidden). ----
    if (t < HID && it > 0) {
      const uint32_t tagc = (uint32_t)it;     // published at iteration it-1
      u64 v[16];
#pragma unroll
      for (int wi = 0; wi < 16; ++wi) v[wi] = pref[wi];
      uint32_t bad = 0u;
#pragma unroll
      for (int wi = 0; wi < 16; ++wi) bad |= ((uint32_t)(v[wi] >> 32)) ^ tagc;
      if (bad != 0u) {                        // prefetch was stale: retry loop
        u64* pc = pbuf + (size_t)((it - 1) & (NSLOT - 1)) * (NWG * HID);
        do {
#pragma unroll
          for (int wi = 0; wi < 16; ++wi)
            v[wi] = __hip_atomic_load(&pc[wi * HID + t],
                                      __ATOMIC_RELAXED, __HIP_MEMORY_SCOPE_AGENT);
          bad = 0u;
#pragma unroll
          for (int wi = 0; wi < 16; ++wi) bad |= ((uint32_t)(v[wi] >> 32)) ^ tagc;
          if (bad != 0u) __builtin_amdgcn_s_sleep(1);
        } while (bad != 0u);
      }
      float gv[16];
#pragma unroll
      for (int wi = 0; wi < 16; ++wi) gv[wi] = __uint_as_float((uint32_t)v[wi]);
      const float gsum = (((gv[0] + gv[1]) + (gv[2] + gv[3]))
                        + ((gv[4] + gv[5]) + (gv[6] + gv[7])))
                       + (((gv[8] + gv[9]) + (gv[10] + gv[11]))
                        + ((gv[12] + gv[13]) + (gv[14] + gv[15])));
      const float c1h = 1.f / (1.f - bp1);    // bp1 = 0.9^it here (pre-advance)
      const float c2h = 1.f / (1.f - bp2);
      const float rh_old = fminf(fmaxf(hh, 0.f), 1.f);
      const float g = (hh >= 0.f && hh <= 1.f) ? (rh_old - bhx - gsum) : 0.f;
      mh = 0.9f * mh + 0.1f * g;
      vh = 0.999f * vh + 0.001f * g * g;
      hh -= eps * (mh * c1h) / (sqrtf(vh * c2h) + 1e-8f);
      rh_s[t] = fminf(fmaxf(hh, 0.f), 1.f);   // rh(it), consumed by Pass A below
    }

    // ---- publish tagged partial (row = rg*16 + cg/4, lanes cg%4==0).
    //      After the check, so the check's implicit vmcnt covers only the prefetch. ----
    if ((cg & 3) == 0) {
      u64* pp = pbuf + (size_t)(it & (NSLOT - 1)) * (NWG * HID)
                     + wg * HID + rg * 16 + (cg >> 2);
      __hip_atomic_store(pp, pk((uint32_t)(it + 1), aB[0]),
                         __ATOMIC_RELAXED, __HIP_MEMORY_SCOPE_AGENT);
    }

    bp1 *= 0.9f; bp2 *= 0.999f;               // now 0.9^(it+1): o-update factors
    const float c1 = 1.f / (1.f - bp1);
    const float c2 = 1.f / (1.f - bp2);

    bar_lgkm();   // B1: rh_s(it) visible to all waves

    // ---- Pass A: r_h @ W2 over this thread's rows ----
    {
      float aA[4] = {0.f, 0.f, 0.f, 0.f};
#pragma unroll
      for (int r = 0; r < 16; ++r) {
        const float rh = rh_s[rg * 16 + r];          // wave-uniform broadcast
#pragma unroll
        for (int k = 0; k < 4; ++k) aA[k] = fmaf(w2[r][k], rh, aA[k]);
      }
#pragma unroll
      for (int k = 0; k < 4; ++k)
        red[rg * SLICE + cg + 64 * k] = aA[k];       // stride-1/lane, conflict-free
    }
    bar_lgkm();   // B2: red visible

    // ---- g_o + Adam(o): one column (= t) per thread, t < SLICE ----
    if (t < SLICE) {
      const float s = ((red[t] + red[SLICE + t]) + (red[2*SLICE + t] + red[3*SLICE + t]))
                    + ((red[4*SLICE + t] + red[5*SLICE + t]) + (red[6*SLICE + t] + red[7*SLICE + t]));
      const float ro_old = fminf(fmaxf(oo, 0.f), 1.f);
      const float g = (oo >= 0.f && oo <= 1.f) ? (ro_old - bo - s) : 0.f;
      mo = 0.9f * mo + 0.1f * g;
      vo = 0.999f * vo + 0.001f * g * g;
      oo -= eps * (mo * c1) / (sqrtf(vo * c2) + 1e-8f);
      ro_s[t] = fminf(fmaxf(oo, 0.f), 1.f);          // ro(it+1), read next iter
    }

    // ---- prefetch next check's slot (tag it+1, published this iteration).
    //      Loads stay in flight across B3 + next PassB; waited only at the check. ----
    if (t < HID && it + 1 < n_iter) {
      const u64* pn = pbuf + (size_t)(it & (NSLOT - 1)) * (NWG * HID);
#pragma unroll
      for (int wi = 0; wi < 16; ++wi)
        pref[wi] = __hip_atomic_load(&pn[wi * HID + t],
                                     __ATOMIC_RELAXED, __HIP_MEMORY_SCOPE_AGENT);
    }

    bar_lgkm();   // B3: ro_s(it+1) visible for next Pass B
  }

  if (t < SLICE) out[wg * SLICE + t] = oo;
}

// ---------------- launcher ----------------------------------------------------------
extern "C" void kernel_launch(void* const* d_in, const int* in_sizes, int n_in,
                              void* d_out, int out_size, void* d_ws, size_t ws_size,
                              hipStream_t stream) {
  const float* x     = (const float*)d_in[0];
  const float* W1    = (const float*)d_in[1];
  const float* W2    = (const float*)d_in[2];
  // d_in[3] = b_in (unused by the reference)
  const float* b_h   = (const float*)d_in[4];
  const float* b_out = (const float*)d_in[5];
  const float* h0    = (const float*)d_in[6];
  const float* o0    = (const float*)d_in[7];
  const int*   nit   = (const int*)d_in[8];
  const float* eps   = (const float*)d_in[9];

  u64*   pbuf = (u64*)d_ws;                         // [4][16][128] u64 = 64 KB
  u64*   xw1p = (u64*)((char*)d_ws + 65536);        // [128][128] u64 = 128 KB
  float* out  = (float*)d_out;

  // no memset needed: poisoned 0xAAAAAAAA tags never match (xw1 tag=1, iter tags=1..n)
  k_all<<<dim3(NWG + NXB), dim3(NT), 0, stream>>>(x, W1, W2, b_h, b_out, h0, o0,
                                                  nit, eps, pbuf, xw1p, out);
}

// Round 10
// 498.502 us; speedup vs baseline: 1.2222x; 1.0009x over previous
//
#include <hip/hip_runtime.h>
#include <stdint.h>

#define HID   128
#define OUT   4096
#define NWG   16          // persistent EP workgroups, slice = 256 cols each
#define SLICE 256         // OUT / NWG
#define NT    512
#define NXB   128         // one-shot xW1 worker blocks
#define RPX   512         // rows per xW1 block (65536 / 128)
#define NSLOT 4           // partial-buffer ring depth (deferred check needs >2)
// LDS pad: total static LDS ~98 KB > 160/2 KB ensures the CP can never co-schedule
// two blocks on one CU -> each EP workgroup owns its CU's VALU/LDS exclusively.
#define REDPAD 22528

typedef unsigned long long u64;
typedef unsigned int v2u __attribute__((ext_vector_type(2)));

__device__ __forceinline__ u64 pk(uint32_t tag, float v) {
  return ((u64)tag << 32) | (u64)__float_as_uint(v);
}

// ---- VALU cross-lane primitives (guide-verified builtins only) -----------------
// permlane32_swap: exchanges vdst.hi32lanes <-> src.lo32lanes; returns both results.
// We sum the two outputs, so the {vdst,src} result-order convention cannot matter:
// sum = a[l]+a[l+32] (lanes<32, row r) / b[l-32]+b[l] (lanes>=32, row r+8).
__device__ __forceinline__ float plane32_fold(float a, float b) {
  const v2u r = __builtin_amdgcn_permlane32_swap(__float_as_uint(a), __float_as_uint(b),
                                                 false, false);
  return __uint_as_float(r.x) + __uint_as_float(r.y);
}
// DPP row_ror:8 (ctrl 0x128): within each 16-lane row, rotate by 8 == lane^8.
__device__ __forceinline__ float dpp_ror8(float x) {
  return __int_as_float(
      __builtin_amdgcn_update_dpp(0, __float_as_int(x), 0x128, 0xF, 0xF, true));
}
// quad_perm {2,3,0,1}=0x4E => xor2 ; {1,0,3,2}=0xB1 => xor1 (final fold stages).
__device__ __forceinline__ float dpp_add_xor2(float x) {
  const int y = __builtin_amdgcn_update_dpp(0, __float_as_int(x), 0x4E, 0xF, 0xF, true);
  return x + __int_as_float(y);
}
__device__ __forceinline__ float dpp_add_xor1(float x) {
  const int y = __builtin_amdgcn_update_dpp(0, __float_as_int(x), 0xB1, 0xF, 0xF, true);
  return x + __int_as_float(y);
}

// lgkm-only barrier: syncs LDS producers/consumers WITHOUT draining vmcnt, so the
// agent-scope publish and the prefetched poll loads stay in flight across it.
// sched_barrier(0) fences stop the compiler from moving memory ops over it (rule #18).
__device__ __forceinline__ void bar_lgkm() {
  __builtin_amdgcn_sched_barrier(0);
  asm volatile("s_waitcnt lgkmcnt(0)" ::: "memory");
  __builtin_amdgcn_s_barrier();
  __builtin_amdgcn_sched_barrier(0);
}

// blockIdx < NWG: persistent EP workgroup. blockIdx >= NWG: one-shot xW1 worker.
__global__ __launch_bounds__(NT, 1) void k_all(
    const float* __restrict__ x,
    const float* __restrict__ W1,
    const float* __restrict__ W2,
    const float* __restrict__ b_h,
    const float* __restrict__ b_out,
    const float* __restrict__ h0,
    const float* __restrict__ o0,
    const int* __restrict__ n_iter_p,
    const float* __restrict__ eps_p,
    u64* __restrict__ pbuf,   // [NSLOT][NWG][HID] tagged h-gradient partials
    u64* __restrict__ xw1p,   // [NXB][HID] tagged xW1 partials
    float* __restrict__ out) {

  // red's tail (REDPAD floats) is never indexed: it exists only to inflate the
  // static LDS footprint past 80 KB (anti-packing guarantee, see #define above).
  __shared__ __attribute__((aligned(16))) float red[8 * SLICE + REDPAD];
  __shared__ __attribute__((aligned(16))) float rh_s[HID];
  __shared__ __attribute__((aligned(16))) float ro_s[SLICE];

  const int t = threadIdx.x;

  if (blockIdx.x >= NWG) {
    // ---------------- xW1 worker: partial of clip(x,0,1) @ W1 over 512 rows ------
    const int b = blockIdx.x - NWG;
    const int c4 = (t & 31) * 4;
    const int rseg = t >> 5;            // 0..15
    const int r0 = b * RPX + rseg * 32;
    float4 acc = make_float4(0.f, 0.f, 0.f, 0.f);
#pragma unroll 8
    for (int k = 0; k < 32; ++k) {
      const int r = r0 + k;
      const float rx = fminf(fmaxf(x[r], 0.f), 1.f);
      const float4 wv = *(const float4*)&W1[(size_t)r * HID + c4];
      acc.x = fmaf(rx, wv.x, acc.x); acc.y = fmaf(rx, wv.y, acc.y);
      acc.z = fmaf(rx, wv.z, acc.z); acc.w = fmaf(rx, wv.w, acc.w);
    }
    *(float4*)&red[rseg * HID + c4] = acc;   // 16*128 = 2048 floats
    __syncthreads();
    if (t < HID) {
      float s = 0.f;
#pragma unroll
      for (int k = 0; k < 16; k += 4)
        s += (red[k*HID + t] + red[(k+1)*HID + t]) + (red[(k+2)*HID + t] + red[(k+3)*HID + t]);
      // fire-and-forget swap: RMW executes at the MALL -> minimal visibility latency
      (void)__hip_atomic_exchange(&xw1p[b * HID + t], pk(1u, s),
                                  __ATOMIC_RELAXED, __HIP_MEMORY_SCOPE_AGENT);
    }
    return;
  }

  // ---------------- persistent EP workgroup ---------------------------------------
  const int wg = blockIdx.x;
  const int cg = t & 63;               // lane id; owns cols cg + 64*k (k=0..3)
  const int rg = t >> 6;               // wave id; owns rows rg*16 .. rg*16+15
  const int n_iter = *n_iter_p;
  const float eps  = *eps_p;

  // ---- W2 chunk into registers: w2[r][k] = W2[rg*16+r][wg*256 + cg + 64k] ----
  float w2[16][4];
  {
    const float* wp = W2 + (size_t)(rg * 16) * OUT + wg * SLICE + cg;
#pragma unroll
    for (int r = 0; r < 16; ++r)
#pragma unroll
      for (int k = 0; k < 4; ++k)
        w2[r][k] = wp[(size_t)r * OUT + 64 * k];
  }
#pragma unroll
  for (int r = 0; r < 16; ++r)
    asm volatile("" : "+v"(w2[r][0]), "+v"(w2[r][1]), "+v"(w2[r][2]), "+v"(w2[r][3]));

  // ---- gather xW1 partials: BATCHED unconditional tagged loads, fixed-order sum ----
  float bhx = 0.f, hh = 0.f, mh = 0.f, vh = 0.f;
  if (t < HID) {
    float s = 0.f;
#pragma unroll 1
    for (int ch = 0; ch < 8; ++ch) {
      u64 v[16];
      for (;;) {
#pragma unroll
        for (int k = 0; k < 16; ++k)
          v[k] = __hip_atomic_load(&xw1p[(ch * 16 + k) * HID + t],
                                   __ATOMIC_RELAXED, __HIP_MEMORY_SCOPE_AGENT);
        uint32_t bad = 0u;
#pragma unroll
        for (int k = 0; k < 16; ++k) bad |= ((uint32_t)(v[k] >> 32)) ^ 1u;
        if (bad == 0u) break;
        __builtin_amdgcn_s_sleep(2);
      }
#pragma unroll
      for (int k = 0; k < 16; ++k) s += __uint_as_float((uint32_t)v[k]);
    }
    bhx = b_h[t] + s;
    hh  = h0[t];
    rh_s[t] = fminf(fmaxf(hh, 0.f), 1.f);
  }
  // o-state: one column per thread for t < SLICE only (SLICE=256 < NT)
  float oo = 0.f, mo = 0.f, vo = 0.f, bo = 0.f;
  if (t < SLICE) {
    oo = o0[wg * SLICE + t];
    bo = b_out[wg * SLICE + t];
    ro_s[t] = fminf(fmaxf(oo, 0.f), 1.f);
  }
  __syncthreads();

  // bp1/bp2 hold 0.9^it / 0.999^it at the deferred-check point (h uses step t1=it);
  // they advance before the o-update (o uses t1=it+1).
  float bp1 = 1.f, bp2 = 1.f;
  u64 pref[16];
#pragma unroll
  for (int wi = 0; wi < 16; ++wi) pref[wi] = 0;   // prefetched partials for next check

  for (int it = 0; it < n_iter; ++it) {
    // ---- Pass B (registers): rows rg*16..+15, partial over this thread's 4 cols ----
    float aB[16];
    {
      float rov[4];
#pragma unroll
      for (int k = 0; k < 4; ++k) rov[k] = ro_s[cg + 64 * k];   // stride-1/lane, conflict-free
#pragma unroll
      for (int r = 0; r < 16; ++r) {
        float a = w2[r][0] * rov[0];
#pragma unroll
        for (int k = 1; k < 4; ++k) a = fmaf(w2[r][k], rov[k], a);
        aB[r] = a;
      }
    }
    // ---- in-wave fold (same tree as R6): xor32 on permlane32_swap (VALU),
    //      xor16 shfl (DS), xor8 DPP row_ror (VALU), xor4 shfl (DS),
    //      xor2/xor1 quad_perm (VALU). Publish map: lanes cg%4==0 hold row cg>>2. ----
    {
#pragma unroll
      for (int r = 0; r < 8; ++r)     // xor32: 16 -> 8 rows (VALU permlane swap)
        aB[r] = plane32_fold(aB[r], aB[r + 8]);
#pragma unroll
      for (int r = 0; r < 4; ++r) {   // xor16: 8 -> 4 (DS shfl, kept)
        const float keep = (cg & 16) ? aB[r + 4] : aB[r];
        const float send = (cg & 16) ? aB[r]     : aB[r + 4];
        aB[r] = keep + __shfl_xor(send, 16, 64);
      }
#pragma unroll
      for (int r = 0; r < 2; ++r) {   // xor8: 4 -> 2 (VALU, row_ror:8 == lane^8)
        const float keep = (cg & 8) ? aB[r + 2] : aB[r];
        const float send = (cg & 8) ? aB[r]     : aB[r + 2];
        aB[r] = keep + dpp_ror8(send);
      }
      {                               // xor4: 2 -> 1 (DS shfl, kept)
        const float keep = (cg & 4) ? aB[1] : aB[0];
        const float send = (cg & 4) ? aB[0] : aB[1];
        aB[0] = keep + __shfl_xor(send, 4, 64);
      }
      aB[0] = dpp_add_xor2(aB[0]);    // lane bits 1,0 (VALU)
      aB[0] = dpp_add_xor1(aB[0]);
    }

    // ---- deferred check: consume PassB(it-1) partials (prefetched last iteration;
    //      ~1600+ cyc of issue-to-wait distance -> MALL load RT fully hidden). ----
    if (t < HID && it > 0) {
      const uint32_t tagc = (uint32_t)it;     // published at iteration it-1
      u64 v[16];
#pragma unroll
      for (int wi = 0; wi < 16; ++wi) v[wi] = pref[wi];
      uint32_t bad = 0u;
#pragma unroll
      for (int wi = 0; wi < 16; ++wi) bad |= ((uint32_t)(v[wi] >> 32)) ^ tagc;
      if (bad != 0u) {                        // prefetch was stale: retry loop
        u64* pc = pbuf + (size_t)((it - 1) & (NSLOT - 1)) * (NWG * HID);
        do {
#pragma unroll
          for (int wi = 0; wi < 16; ++wi)
            v[wi] = __hip_atomic_load(&pc[wi * HID + t],
                                      __ATOMIC_RELAXED, __HIP_MEMORY_SCOPE_AGENT);
          bad = 0u;
#pragma unroll
          for (int wi = 0; wi < 16; ++wi) bad |= ((uint32_t)(v[wi] >> 32)) ^ tagc;
          if (bad != 0u) __builtin_amdgcn_s_sleep(1);
        } while (bad != 0u);
      }
      float gv[16];
#pragma unroll
      for (int wi = 0; wi < 16; ++wi) gv[wi] = __uint_as_float((uint32_t)v[wi]);
      const float gsum = (((gv[0] + gv[1]) + (gv[2] + gv[3]))
                        + ((gv[4] + gv[5]) + (gv[6] + gv[7])))
                       + (((gv[8] + gv[9]) + (gv[10] + gv[11]))
                        + ((gv[12] + gv[13]) + (gv[14] + gv[15])));
      const float c1h = 1.f / (1.f - bp1);    // bp1 = 0.9^it here (pre-advance)
      const float c2h = 1.f / (1.f - bp2);
      const float rh_old = fminf(fmaxf(hh, 0.f), 1.f);
      const float g = (hh >= 0.f && hh <= 1.f) ? (rh_old - bhx - gsum) : 0.f;
      mh = 0.9f * mh + 0.1f * g;
      vh = 0.999f * vh + 0.001f * g * g;
      hh -= eps * (mh * c1h) / (sqrtf(vh * c2h) + 1e-8f);
      rh_s[t] = fminf(fmaxf(hh, 0.f), 1.f);   // rh(it), consumed by Pass A below
    }

    // ---- publish tagged partial (row = rg*16 + cg/4, lanes cg%4==0) via
    //      FIRE-AND-FORGET ATOMIC SWAP: the RMW executes at the MALL coherence
    //      point, so visibility ~= one-way fabric latency instead of the relaxed
    //      store's write-back queue delay (R8/R9 localized Vs > ~1800 cyc). ----
    if ((cg & 3) == 0) {
      u64* pp = pbuf + (size_t)(it & (NSLOT - 1)) * (NWG * HID)
                     + wg * HID + rg * 16 + (cg >> 2);
      (void)__hip_atomic_exchange(pp, pk((uint32_t)(it + 1), aB[0]),
                                  __ATOMIC_RELAXED, __HIP_MEMORY_SCOPE_AGENT);
    }

    bp1 *= 0.9f; bp2 *= 0.999f;               // now 0.9^(it+1): o-update factors
    const float c1 = 1.f / (1.f - bp1);
    const float c2 = 1.f / (1.f - bp2);

    bar_lgkm();   // B1: rh_s(it) visible to all waves

    // ---- Pass A: r_h @ W2 over this thread's rows ----
    {
      float aA[4] = {0.f, 0.f, 0.f, 0.f};
#pragma unroll
      for (int r = 0; r < 16; ++r) {
        const float rh = rh_s[rg * 16 + r];          // wave-uniform broadcast
#pragma unroll
        for (int k = 0; k < 4; ++k) aA[k] = fmaf(w2[r][k], rh, aA[k]);
      }
#pragma unroll
      for (int k = 0; k < 4; ++k)
        red[rg * SLICE + cg + 64 * k] = aA[k];       // stride-1/lane, conflict-free
    }
    bar_lgkm();   // B2: red visible

    // ---- g_o + Adam(o): one column (= t) per thread, t < SLICE ----
    if (t < SLICE) {
      const float s = ((red[t] + red[SLICE + t]) + (red[2*SLICE + t] + red[3*SLICE + t]))
                    + ((red[4*SLICE + t] + red[5*SLICE + t]) + (red[6*SLICE + t] + red[7*SLICE + t]));
      const float ro_old = fminf(fmaxf(oo, 0.f), 1.f);
      const float g = (oo >= 0.f && oo <= 1.f) ? (ro_old - bo - s) : 0.f;
      mo = 0.9f * mo + 0.1f * g;
      vo = 0.999f * vo + 0.001f * g * g;
      oo -= eps * (mo * c1) / (sqrtf(vo * c2) + 1e-8f);
      ro_s[t] = fminf(fmaxf(oo, 0.f), 1.f);          // ro(it+1), read next iter
    }

    // ---- prefetch next check's slot (tag it+1, published this iteration).
    //      Loads stay in flight across B3 + next PassB; waited only at the check. ----
    if (t < HID && it + 1 < n_iter) {
      const u64* pn = pbuf + (size_t)(it & (NSLOT - 1)) * (NWG * HID);
#pragma unroll
      for (int wi = 0; wi < 16; ++wi)
        pref[wi] = __hip_atomic_load(&pn[wi * HID + t],
                                     __ATOMIC_RELAXED, __HIP_MEMORY_SCOPE_AGENT);
    }

    bar_lgkm();   // B3: ro_s(it+1) visible for next Pass B
  }

  if (t < SLICE) out[wg * SLICE + t] = oo;
}

// ---------------- launcher ----------------------------------------------------------
extern "C" void kernel_launch(void* const* d_in, const int* in_sizes, int n_in,
                              void* d_out, int out_size, void* d_ws, size_t ws_size,
                              hipStream_t stream) {
  const float* x     = (const float*)d_in[0];
  const float* W1    = (const float*)d_in[1];
  const float* W2    = (const float*)d_in[2];
  // d_in[3] = b_in (unused by the reference)
  const float* b_h   = (const float*)d_in[4];
  const float* b_out = (const float*)d_in[5];
  const float* h0    = (const float*)d_in[6];
  const float* o0    = (const float*)d_in[7];
  const int*   nit   = (const int*)d_in[8];
  const float* eps   = (const float*)d_in[9];

  u64*   pbuf = (u64*)d_ws;                         // [4][16][128] u64 = 64 KB
  u64*   xw1p = (u64*)((char*)d_ws + 65536);        // [128][128] u64 = 128 KB
  float* out  = (float*)d_out;

  // no memset needed: poisoned 0xAAAAAAAA tags never match (xw1 tag=1, iter tags=1..n)
  k_all<<<dim3(NWG + NXB), dim3(NT), 0, stream>>>(x, W1, W2, b_h, b_out, h0, o0,
                                                  nit, eps, pbuf, xw1p, out);
}